// Round 4
// baseline (315.341 us; speedup 1.0000x reference)
//
#include <hip/hip_runtime.h>
#include <hip/hip_bf16.h>

#define EMB 512
#define NHEADS 8
#define HD 64
#define SEQ 2048

typedef float f32x4 __attribute__((ext_vector_type(4)));
typedef short short8 __attribute__((ext_vector_type(8)));
typedef unsigned short ushort4_t __attribute__((ext_vector_type(4)));

#define MFMA(a, b, c) __builtin_amdgcn_mfma_f32_16x16x32_bf16((a), (b), (c), 0, 0, 0)

__device__ inline unsigned short f2bf(float f) {
    union { float f; unsigned u; } v; v.f = f;
    unsigned r = v.u + 0x7fffu + ((v.u >> 16) & 1u);   // round-to-nearest-even
    return (unsigned short)(r >> 16);
}

__device__ inline short8 f8_to_bf8(float4 a, float4 b) {
    short8 r;
    r[0] = (short)f2bf(a.x); r[1] = (short)f2bf(a.y);
    r[2] = (short)f2bf(a.z); r[3] = (short)f2bf(a.w);
    r[4] = (short)f2bf(b.x); r[5] = (short)f2bf(b.y);
    r[6] = (short)f2bf(b.z); r[7] = (short)f2bf(b.w);
    return r;
}

// ---------------------------------------------------------------------------
// Kernel 1: per-head QKV projection. grid.x = N*H*(S/64), grid.y = 3 (q,k,v)
// q output pre-scaled by log2(e)/8 (softmax scale folded in, exp2 domain).
// v output written TRANSPOSED: vt[n][h][d][s].
// ---------------------------------------------------------------------------
__global__ __launch_bounds__(256) void qkv_proj_kernel(
    const float* __restrict__ vin, const float* __restrict__ kin,
    const float* __restrict__ qin,
    const float* __restrict__ Wv, const float* __restrict__ Wk,
    const float* __restrict__ Wq,
    unsigned short* __restrict__ q_ws, unsigned short* __restrict__ k_ws,
    unsigned short* __restrict__ vt_ws)
{
    const int z = blockIdx.y;
    const float* __restrict__ x = (z == 0) ? qin : (z == 1 ? kin : vin);
    const float* __restrict__ W = (z == 0) ? Wq : (z == 1 ? Wk : Wv);

    const int bid = blockIdx.x;
    const int st = bid & 31;            // S/64 = 32 tiles
    const int h  = (bid >> 5) & 7;
    const int n  = bid >> 8;

    const int lane = threadIdx.x & 63;
    const int w    = threadIdx.x >> 6;
    const int lo = lane & 15, hi = lane >> 4;
    const int s_base = st * 64 + w * 16;

    const float* xr = x + ((size_t)n * SEQ + s_base + lo) * EMB + h * HD;
    short8 a[2];
#pragma unroll
    for (int kb = 0; kb < 2; ++kb) {
        const float4* p = (const float4*)(xr + kb * 32 + hi * 8);
        a[kb] = f8_to_bf8(p[0], p[1]);
    }
    short8 b[2][4];
#pragma unroll
    for (int nb = 0; nb < 4; ++nb) {
        const float* wr = W + (lo + 16 * nb) * HD;
#pragma unroll
        for (int kb = 0; kb < 2; ++kb) {
            const float4* p = (const float4*)(wr + kb * 32 + hi * 8);
            b[kb][nb] = f8_to_bf8(p[0], p[1]);
        }
    }
    f32x4 acc[4];
#pragma unroll
    for (int nb = 0; nb < 4; ++nb) {
        f32x4 t = {0.f, 0.f, 0.f, 0.f};
        t = MFMA(a[0], b[0][nb], t);
        t = MFMA(a[1], b[1][nb], t);
        acc[nb] = t;
    }
    const size_t nh = (size_t)n * NHEADS + h;
    if (z < 2) {
        const float sc = (z == 0) ? 0.18033688011112042f : 1.0f; // log2(e)/8
        unsigned short* o = (z == 0 ? q_ws : k_ws) + nh * SEQ * HD;
#pragma unroll
        for (int nb = 0; nb < 4; ++nb)
#pragma unroll
            for (int i = 0; i < 4; ++i)
                o[(size_t)(s_base + hi * 4 + i) * HD + lo + 16 * nb] =
                    f2bf(acc[nb][i] * sc);
    } else {
        unsigned short* o = vt_ws + nh * HD * SEQ;
#pragma unroll
        for (int nb = 0; nb < 4; ++nb) {
            ushort4_t pk;
            pk[0] = f2bf(acc[nb][0]); pk[1] = f2bf(acc[nb][1]);
            pk[2] = f2bf(acc[nb][2]); pk[3] = f2bf(acc[nb][3]);
            *(ushort4_t*)(o + (size_t)(lo + 16 * nb) * SEQ + s_base + hi * 4) = pk;
        }
    }
}

// ---------------------------------------------------------------------------
// Kernel 2: Wo fp32 -> bf16
// ---------------------------------------------------------------------------
__global__ __launch_bounds__(256) void wconv_kernel(
    const float* __restrict__ Wo, unsigned short* __restrict__ wob)
{
    const int idx = (blockIdx.x * 256 + threadIdx.x) * 8;
    const float4* p = (const float4*)(Wo + idx);
    short8 r = f8_to_bf8(p[0], p[1]);
    *(short8*)(wob + idx) = r;
}

// ---------------------------------------------------------------------------
// Kernel 3: flash attention, no-max softmax (scores bounded; masked -> exp2(-1e30)=0),
// software-pipelined K/mask prefetch + early V issue, XCD-bijective swizzle.
// 1 wave = 16 q-rows; 4 waves/block share (n,h) K/V stream (same XCD L2).
// ---------------------------------------------------------------------------
__global__ __launch_bounds__(256) void attn_kernel(
    const unsigned short* __restrict__ q_ws, const unsigned short* __restrict__ k_ws,
    const unsigned short* __restrict__ vt_ws, const int* __restrict__ mask,
    unsigned short* __restrict__ ao_ws)
{
    __shared__ __align__(16) unsigned short plds[4][16][72]; // padded rows

    const int lane = threadIdx.x & 63;
    const int w = threadIdx.x >> 6;
    const int lo = lane & 15, hi = lane >> 4;
    // XCD swizzle: grid=1024 (multiple of 8) -> blocks sharing (n,h) on one XCD
    const int bid = (blockIdx.x & 7) * 128 + (blockIdx.x >> 3);
    const int wid = bid * 4 + w;
    const int qt = wid & 127;          // S/16 = 128 q-tiles
    const int h  = (wid >> 7) & 7;
    const int n  = wid >> 10;
    const size_t nh = (size_t)n * NHEADS + h;

    const unsigned short* qp = q_ws + nh * SEQ * HD;
    const unsigned short* kp = k_ws + nh * SEQ * HD;
    const unsigned short* vp = vt_ws + nh * HD * SEQ;
    const int* mp = mask + (size_t)n * SEQ;

    const int q0 = qt * 16;
    short8 aq[2];
#pragma unroll
    for (int kb = 0; kb < 2; ++kb)
        aq[kb] = *(const short8*)(qp + (size_t)(q0 + lo) * HD + kb * 32 + hi * 8);

    f32x4 o[4];
    float lacc[4];
#pragma unroll
    for (int nb = 0; nb < 4; ++nb) o[nb] = (f32x4){0.f, 0.f, 0.f, 0.f};
#pragma unroll
    for (int i = 0; i < 4; ++i) lacc[i] = 0.f;

    short8 kA[4][2], kB[4][2];
    int mA[4], mB[4];
    // prologue: K tile 0 + mask 0
#pragma unroll
    for (int nb = 0; nb < 4; ++nb) {
        const unsigned short* kr = kp + (size_t)(lo + 16 * nb) * HD + hi * 8;
        kA[nb][0] = *(const short8*)kr;
        kA[nb][1] = *(const short8*)(kr + 32);
        mA[nb] = mp[lo + 16 * nb];
    }

#define ATTN_ITER(KT, KC, KN, MC, MN) do {                                        \
        const int kt_ = (KT) * 64;                                                \
        const int ktn = ((KT) == 31 ? 0 : (KT) + 1) * 64;                         \
        /* prefetch next K tile + next mask (consumed next iteration) */          \
        _Pragma("unroll")                                                         \
        for (int nb = 0; nb < 4; ++nb) {                                          \
            const unsigned short* kr = kp + (size_t)(ktn + lo + 16 * nb) * HD + hi * 8; \
            KN[nb][0] = *(const short8*)kr;                                       \
            KN[nb][1] = *(const short8*)(kr + 32);                                \
            MN[nb] = mp[ktn + lo + 16 * nb];                                      \
        }                                                                         \
        /* V for this tile: issue early, consumed after softmax */                \
        short8 v0[4], v1[4];                                                      \
        _Pragma("unroll")                                                         \
        for (int nb = 0; nb < 4; ++nb) {                                          \
            const unsigned short* vr = vp + (size_t)(lo + 16 * nb) * SEQ + kt_ + hi * 8; \
            v0[nb] = *(const short8*)vr;                                          \
            v1[nb] = *(const short8*)(vr + 32);                                   \
        }                                                                         \
        /* S = Q K^T (exp2 domain, scale folded into q) */                        \
        f32x4 e[4];                                                               \
        _Pragma("unroll")                                                         \
        for (int nb = 0; nb < 4; ++nb) {                                          \
            f32x4 t = {0.f, 0.f, 0.f, 0.f};                                       \
            t = MFMA(aq[0], KC[nb][0], t);                                        \
            t = MFMA(aq[1], KC[nb][1], t);                                        \
            e[nb] = t;                                                            \
        }                                                                         \
        /* no-max softmax: P = exp2(S); masked keys -> exp2(-1e30) = 0 */         \
        _Pragma("unroll")                                                         \
        for (int i = 0; i < 4; ++i) {                                             \
            float ps = 0.f;                                                       \
            _Pragma("unroll")                                                     \
            for (int nb = 0; nb < 4; ++nb) {                                      \
                float sv = (MC[nb] == 0) ? -1e30f : e[nb][i];                     \
                float p = __builtin_amdgcn_exp2f(sv);                             \
                ps += p;                                                          \
                plds[w][hi * 4 + i][lo + 16 * nb] = f2bf(p);                      \
            }                                                                     \
            lacc[i] += ps;                                                        \
        }                                                                         \
        /* P fragment transpose via per-wave LDS (in-order same-wave DS) */       \
        short8 pa0 = *(const short8*)(&plds[w][lo][hi * 8]);                      \
        short8 pa1 = *(const short8*)(&plds[w][lo][32 + hi * 8]);                 \
        _Pragma("unroll")                                                         \
        for (int nb = 0; nb < 4; ++nb) {                                          \
            o[nb] = MFMA(pa0, v0[nb], o[nb]);                                     \
            o[nb] = MFMA(pa1, v1[nb], o[nb]);                                     \
        }                                                                         \
    } while (0)

    for (int kt2 = 0; kt2 < 32; kt2 += 2) {
        ATTN_ITER(kt2,     kA, kB, mA, mB);
        ATTN_ITER(kt2 + 1, kB, kA, mB, mA);
    }
#undef ATTN_ITER

    // final l reduction across the 16-lane group + normalize
#pragma unroll
    for (int off = 1; off < 16; off <<= 1)
#pragma unroll
        for (int i = 0; i < 4; ++i)
            lacc[i] += __shfl_xor(lacc[i], off);
    float linv[4];
#pragma unroll
    for (int i = 0; i < 4; ++i) linv[i] = 1.0f / lacc[i];

    unsigned short* op = ao_ws + ((size_t)n * SEQ + q0) * EMB + h * HD;
#pragma unroll
    for (int nb = 0; nb < 4; ++nb)
#pragma unroll
        for (int i = 0; i < 4; ++i)
            op[(size_t)(hi * 4 + i) * EMB + lo + 16 * nb] = f2bf(o[nb][i] * linv[i]);
}

// ---------------------------------------------------------------------------
// Kernel 4: output projection  out = ao @ Wo.T + bo   (fp32 out)
// ---------------------------------------------------------------------------
__global__ __launch_bounds__(256) void out_proj_kernel(
    const unsigned short* __restrict__ ao_ws, const unsigned short* __restrict__ wob,
    const float* __restrict__ bo, float* __restrict__ out)
{
    const int bid = blockIdx.x;
    const int nc = bid & 7;            // EMB/64 = 8 col tiles
    const int mt = bid >> 3;
    const int lane = threadIdx.x & 63;
    const int w = threadIdx.x >> 6;
    const int lo = lane & 15, hi = lane >> 4;
    const int m0 = mt * 64 + w * 16;
    const int e0 = nc * 64;

    f32x4 acc[4];
#pragma unroll
    for (int nb = 0; nb < 4; ++nb) acc[nb] = (f32x4){0.f, 0.f, 0.f, 0.f};

    const unsigned short* ar = ao_ws + (size_t)(m0 + lo) * EMB;
    for (int k0 = 0; k0 < EMB; k0 += 32) {
        short8 a = *(const short8*)(ar + k0 + hi * 8);
#pragma unroll
        for (int nb = 0; nb < 4; ++nb) {
            short8 b = *(const short8*)(wob + (size_t)(e0 + lo + 16 * nb) * EMB + k0 + hi * 8);
            acc[nb] = MFMA(a, b, acc[nb]);
        }
    }
#pragma unroll
    for (int nb = 0; nb < 4; ++nb) {
        float bias = bo[e0 + lo + 16 * nb];
#pragma unroll
        for (int i = 0; i < 4; ++i)
            out[(size_t)(m0 + hi * 4 + i) * EMB + e0 + lo + 16 * nb] = acc[nb][i] + bias;
    }
}

// ---------------------------------------------------------------------------
extern "C" void kernel_launch(void* const* d_in, const int* in_sizes, int n_in,
                              void* d_out, int out_size, void* d_ws, size_t ws_size,
                              hipStream_t stream)
{
    const float* vin = (const float*)d_in[0];
    const float* kin = (const float*)d_in[1];
    const float* qin = (const float*)d_in[2];
    const int*  mask = (const int*)d_in[3];
    const float* Wv  = (const float*)d_in[4];
    const float* Wk  = (const float*)d_in[5];
    const float* Wq  = (const float*)d_in[6];
    const float* Wo  = (const float*)d_in[7];
    const float* bo  = (const float*)d_in[8];
    float* out = (float*)d_out;

    const int N = in_sizes[0] / (SEQ * EMB);   // 4

    char* ws = (char*)d_ws;
    const size_t qkv_bytes = (size_t)N * NHEADS * SEQ * HD * 2;  // 8.39 MB each
    unsigned short* q_ws  = (unsigned short*)(ws);
    unsigned short* k_ws  = (unsigned short*)(ws + qkv_bytes);
    unsigned short* vt_ws = (unsigned short*)(ws + 2 * qkv_bytes);
    unsigned short* ao_ws = (unsigned short*)(ws + 3 * qkv_bytes);
    unsigned short* wob   = (unsigned short*)(ws + 4 * qkv_bytes);

    hipLaunchKernelGGL(wconv_kernel, dim3(EMB * EMB / 2048), dim3(256), 0, stream,
                       Wo, wob);
    hipLaunchKernelGGL(qkv_proj_kernel, dim3(N * NHEADS * (SEQ / 64), 3), dim3(256), 0, stream,
                       vin, kin, qin, Wv, Wk, Wq, q_ws, k_ws, vt_ws);
    hipLaunchKernelGGL(attn_kernel, dim3(N * NHEADS * (SEQ / 16) / 4), dim3(256), 0, stream,
                       q_ws, k_ws, vt_ws, mask, ao_ws);
    hipLaunchKernelGGL(out_proj_kernel, dim3((N * SEQ / 64) * (EMB / 64)), dim3(256), 0, stream,
                       ao_ws, wob, bo, out);
}